// Round 4
// baseline (1074.037 us; speedup 1.0000x reference)
//
#include <hip/hip_runtime.h>
#include <math.h>

#define NN 100000
#define NE 1600000
#define DD 32
#define CC 16
#define SCAN_B 391  // ceil(NN/256)

typedef unsigned short bf16_t;
struct us4 { bf16_t x, y, z, w; };

static inline unsigned gblocks(long total) { return (unsigned)((total + 255) / 256); }

__device__ inline bf16_t f2bf(float f) {
    unsigned u = __float_as_uint(f);
    u += 0x7fffu + ((u >> 16) & 1u);
    return (bf16_t)(u >> 16);
}
__device__ inline float bf2f(bf16_t h) { return __uint_as_float(((unsigned)h) << 16); }

__global__ void zero_int_k(int* p, int n) {
    int i = blockIdx.x * 256 + threadIdx.x;
    if (i < n) p[i] = 0;
}

__global__ void hist_k(const int* __restrict__ dst, int* __restrict__ cnt) {
    int e = blockIdx.x * 256 + threadIdx.x;
    if (e < NE) atomicAdd(&cnt[dst[e]], 1);
}

// block-local inclusive scan of counts -> offs[g+1], block sums -> bsum
__global__ void s1_k(const int* __restrict__ cnt, int* __restrict__ offs,
                     int* __restrict__ bsum) {
    __shared__ int sm[256];
    int t = threadIdx.x, b = blockIdx.x;
    int g = b * 256 + t;
    int v = (g < NN) ? cnt[g] : 0;
    sm[t] = v;
    __syncthreads();
    for (int o = 1; o < 256; o <<= 1) {
        int u = (t >= o) ? sm[t - o] : 0;
        __syncthreads();
        sm[t] += u;
        __syncthreads();
    }
    if (g < NN) offs[g + 1] = sm[t];
    if (t == 255) bsum[b] = sm[255];
}

// single-block scan of block sums -> exclusive prefixes
__global__ void s2_k(int* __restrict__ bsum) {
    __shared__ int sm[512];
    int t = threadIdx.x;
    int v = (t < SCAN_B) ? bsum[t] : 0;
    sm[t] = v;
    __syncthreads();
    for (int o = 1; o < 512; o <<= 1) {
        int u = (t >= o) ? sm[t - o] : 0;
        __syncthreads();
        sm[t] += u;
        __syncthreads();
    }
    if (t < SCAN_B) bsum[t] = sm[t] - v;  // exclusive
}

__global__ void s3_k(int* __restrict__ offs, const int* __restrict__ bsum) {
    int t = threadIdx.x, b = blockIdx.x;
    int g = b * 256 + t;
    if (g < NN) offs[g + 1] += bsum[b];
    if (g == 0) offs[0] = 0;
}

__global__ void copyoff_k(const int* __restrict__ offs, int* __restrict__ cur) {
    int g = blockIdx.x * 256 + threadIdx.x;
    if (g < NN) cur[g] = offs[g];
}

__global__ void fill_k(const int* __restrict__ dst, int* __restrict__ cur,
                       int* __restrict__ perm) {
    int e = blockIdx.x * 256 + threadIdx.x;
    if (e < NE) {
        int pos = atomicAdd(&cur[dst[e]], 1);
        perm[pos] = e;
    }
}

// y[k][n][e] = x[n,:] @ W[k][:,e]  (k-major planes -> fully contiguous writes)
template<int K>
__global__ __launch_bounds__(256) void y3_k(const float* __restrict__ x,
                                            const float* __restrict__ W,
                                            us4* __restrict__ y) {
    __shared__ float xs[128 * 36];
    const int k = blockIdx.y;
    const long n0 = (long)blockIdx.x * 128;
    const int tid = threadIdx.x;

#pragma unroll
    for (int i = 0; i < 4; ++i) {
        int idx = tid + 256 * i;
        int row = idx >> 3;
        int c4 = idx & 7;
        long n = n0 + row;
        float4 v = make_float4(0.f, 0.f, 0.f, 0.f);
        if (n < NN) v = ((const float4*)x)[n * 8 + c4];
        *(float4*)&xs[row * 36 + c4 * 4] = v;
    }
    __syncthreads();

    const int eq = tid & 7;
    const int nl = tid >> 3;
    const float4* Wk = (const float4*)(W + (long)k * DD * DD) + eq;

    float4 a0 = make_float4(0, 0, 0, 0), a1 = a0, a2 = a0, a3 = a0;
#pragma unroll
    for (int d4 = 0; d4 < 8; ++d4) {
        float4 w0 = Wk[(4 * d4 + 0) * 8];
        float4 w1 = Wk[(4 * d4 + 1) * 8];
        float4 w2 = Wk[(4 * d4 + 2) * 8];
        float4 w3 = Wk[(4 * d4 + 3) * 8];
#pragma unroll
        for (int j = 0; j < 4; ++j) {
            float4 xv = *(const float4*)&xs[(nl + 32 * j) * 36 + d4 * 4];
            float4& a = j == 0 ? a0 : j == 1 ? a1 : j == 2 ? a2 : a3;
            a.x = fmaf(xv.x, w0.x, a.x); a.y = fmaf(xv.x, w0.y, a.y);
            a.z = fmaf(xv.x, w0.z, a.z); a.w = fmaf(xv.x, w0.w, a.w);
            a.x = fmaf(xv.y, w1.x, a.x); a.y = fmaf(xv.y, w1.y, a.y);
            a.z = fmaf(xv.y, w1.z, a.z); a.w = fmaf(xv.y, w1.w, a.w);
            a.x = fmaf(xv.z, w2.x, a.x); a.y = fmaf(xv.z, w2.y, a.y);
            a.z = fmaf(xv.z, w2.z, a.z); a.w = fmaf(xv.z, w2.w, a.w);
            a.x = fmaf(xv.w, w3.x, a.x); a.y = fmaf(xv.w, w3.y, a.y);
            a.z = fmaf(xv.w, w3.z, a.z); a.w = fmaf(xv.w, w3.w, a.w);
        }
    }

#pragma unroll
    for (int j = 0; j < 4; ++j) {
        long n = n0 + nl + 32 * j;
        if (n >= NN) continue;
        float4 a = j == 0 ? a0 : j == 1 ? a1 : j == 2 ? a2 : a3;
        us4 o; o.x = f2bf(a.x); o.y = f2bf(a.y); o.z = f2bf(a.z); o.w = f2bf(a.w);
        y[((long)k * NN + n) * 8 + eq] = o;  // contiguous 512B per wave
    }
}

// CSR aggregation + fused finalize: one 32-lane group per dst node.
// acc[e] in registers, no atomics; mean from CSR degree; + x@root + bias; ELU.
template<int KS>
__global__ __launch_bounds__(256) void agg_k(
        const int* __restrict__ offs, const int* __restrict__ perm,
        const int* __restrict__ src, const float* __restrict__ attr,
        const bf16_t* __restrict__ y, const float* __restrict__ xin,
        const float* __restrict__ root, const float* __restrict__ bias,
        float* __restrict__ h) {
    const int lane = threadIdx.x & 31;
    const int grp = threadIdx.x >> 5;
    const int n = blockIdx.x * 8 + grp;
    if (n >= NN) return;
    const int j0 = offs[n], j1 = offs[n + 1];
    float acc = 0.f;
    const float2* at2 = (const float2*)attr;
    for (int j = j0; j < j1; ++j) {
        int ed = perm[j];
        int s = src[ed];
        float2 uv = at2[ed];
        float v0 = uv.x * (KS - 1), v1 = uv.y * (KS - 1);
        float fb0 = floorf(v0), fb1 = floorf(v1);
        float f0 = v0 - fb0, f1 = v1 - fb1;
        int i0 = min((int)fb0, KS - 1), i1 = min((int)fb1, KS - 1);
        int q0 = min(i0 + 1, KS - 1), q1 = min(i1 + 1, KS - 1);
        long sb = (long)s * DD + lane;
        float y00 = bf2f(y[(long)(i0 + i1 * KS) * NN * DD + sb]);
        float y10 = bf2f(y[(long)(q0 + i1 * KS) * NN * DD + sb]);
        float y01 = bf2f(y[(long)(i0 + q1 * KS) * NN * DD + sb]);
        float y11 = bf2f(y[(long)(q0 + q1 * KS) * NN * DD + sb]);
        acc += (1.f - f0) * (1.f - f1) * y00 + f0 * (1.f - f1) * y10
             + (1.f - f0) * f1 * y01 + f0 * f1 * y11;
    }
    float deg = (float)(j1 - j0);
    if (deg < 1.f) deg = 1.f;
    float xv = xin[(long)n * DD + lane];
    float acc2 = 0.f;
#pragma unroll
    for (int d = 0; d < DD; ++d)
        acc2 = fmaf(__shfl(xv, d, 32), root[d * DD + lane], acc2);
    float v = acc / deg + acc2 + bias[lane];
    h[(long)n * DD + lane] = v > 0.f ? v : expm1f(v);
}

// fused 2-layer MLP head: one 32-lane group per node
__global__ __launch_bounds__(256) void mlp_k(
        const float* __restrict__ h, const float* __restrict__ w1,
        const float* __restrict__ b1, const float* __restrict__ w2,
        const float* __restrict__ b2, float* __restrict__ out) {
    const int lane = threadIdx.x & 31;
    const int grp = threadIdx.x >> 5;
    const int n = blockIdx.x * 8 + grp;
    if (n >= NN) return;
    float hv = h[(long)n * DD + lane];
    float t = b1[lane];
#pragma unroll
    for (int d = 0; d < DD; ++d)
        t = fmaf(__shfl(hv, d, 32), w1[d * DD + lane], t);
    t = fmaxf(t, 0.f);
    int c = lane & (CC - 1);
    float o = 0.f;
#pragma unroll
    for (int d = 0; d < DD; ++d)
        o = fmaf(__shfl(t, d, 32), w2[d * CC + c], o);
    o += b2[c];
    o = fmaxf(o, 0.f);
    if (lane < CC) out[(long)n * CC + lane] = o;
}

extern "C" void kernel_launch(void* const* d_in, const int* in_sizes, int n_in,
                              void* d_out, int out_size, void* d_ws, size_t ws_size,
                              hipStream_t stream) {
    const float* x     = (const float*)d_in[0];
    const int*   ei    = (const int*)d_in[1];
    const float* attr  = (const float*)d_in[2];
    const float* W1    = (const float*)d_in[3];
    const float* root1 = (const float*)d_in[4];
    const float* bias1 = (const float*)d_in[5];
    const float* W2    = (const float*)d_in[6];
    const float* root2 = (const float*)d_in[7];
    const float* bias2 = (const float*)d_in[8];
    const float* m1w   = (const float*)d_in[9];
    const float* m1b   = (const float*)d_in[10];
    const float* m2w   = (const float*)d_in[11];
    const float* m2b   = (const float*)d_in[12];
    float* out = (float*)d_out;

    const int* srcp = ei;
    const int* dstp = ei + NE;

    // ws: offs(NN+2 incl pad) | cur(NN) | bsum(512) | perm(NE) | h1 | h2 | y(bf16)
    int* offs = (int*)d_ws;
    int* cur  = offs + NN + 2;
    int* bsum = cur + NN;
    int* perm = bsum + 512;
    float* h1 = (float*)(perm + NE);
    float* h2 = h1 + (size_t)NN * DD;
    bf16_t* y = (bf16_t*)(h2 + (size_t)NN * DD);
    // total: 4*(100002+100000+512+1600000+3200000+3200000) + 160MB = 192.8MB

    // ---- CSR build ----
    zero_int_k<<<gblocks(NN), 256, 0, stream>>>(cur, NN);
    hist_k<<<gblocks(NE), 256, 0, stream>>>(dstp, cur);
    s1_k<<<SCAN_B, 256, 0, stream>>>(cur, offs, bsum);
    s2_k<<<1, 512, 0, stream>>>(bsum);
    s3_k<<<SCAN_B, 256, 0, stream>>>(offs, bsum);
    copyoff_k<<<SCAN_B, 256, 0, stream>>>(offs, cur);
    fill_k<<<gblocks(NE), 256, 0, stream>>>(dstp, cur, perm);

    const unsigned gy = (NN + 127) / 128;
    const unsigned gn = (NN + 7) / 8;

    // ---- layer 1 (ksize=3, K=9) ----
    y3_k<9><<<dim3(gy, 9), 256, 0, stream>>>(x, W1, (us4*)y);
    agg_k<3><<<gn, 256, 0, stream>>>(offs, perm, srcp, attr, y, x, root1, bias1, h1);

    // ---- layer 2 (ksize=5, K=25) ----
    y3_k<25><<<dim3(gy, 25), 256, 0, stream>>>(h1, W2, (us4*)y);
    agg_k<5><<<gn, 256, 0, stream>>>(offs, perm, srcp, attr, y, h1, root2, bias2, h2);

    // ---- fused MLP head ----
    mlp_k<<<gn, 256, 0, stream>>>(h2, m1w, m1b, m2w, m2b, out);
}